// Round 4
// baseline (312.971 us; speedup 1.0000x reference)
//
#include <hip/hip_runtime.h>
#include <hip/hip_bf16.h>
#include <stdint.h>

#define MROWS 32
#define LDA   264   // Abuf stride in bf16 elems: 528 B/row (16B-aligned, bank-skewed)
#define FMS   40    // fmA stride in bf16 elems (80 B, 16B-aligned)

typedef __bf16 bf16x8 __attribute__((ext_vector_type(8)));
typedef float  f32x4  __attribute__((ext_vector_type(4)));

__device__ __forceinline__ unsigned short f2bf(float f) {
    union { float f; uint32_t u; } v; v.f = f;
    return (unsigned short)((v.u + 0x7FFFu + ((v.u >> 16) & 1u)) >> 16);
}

__device__ __forceinline__ ushort2 pk_bf16(float a, float b) {
    union { __hip_bfloat162 v; ushort2 u; } c;
    c.v = __float22bfloat162_rn(make_float2(a, b));
    return c.u;
}

// tanh-form GeLU via sigmoid; explicit rcp (avoids IEEE div sequence).
// max abs deviation from exact-erf gelu ~3e-4.
__device__ __forceinline__ float gelu_fast(float v) {
    const float t = v * v;
    const float p = fmaf(0.044715f, t, 1.0f);
    const float u = v * p;
    const float e = __builtin_amdgcn_exp2f(u * -2.3021131160186336f);  // exp(-2*0.79788456*u)
    return v * __builtin_amdgcn_rcpf(1.0f + e);
}

// prep: blocks 0..255 -> w1t (bf16 W1^T, n-major k-contig)
//       block 256     -> sqb  (fp32 step_q + b_fm, 24x256)
//       block 257     -> wfmt (bf16 W_fm^T, n-major k-contig, k padded 16->32 with zeros)
__global__ __launch_bounds__(256) void prep(const float* __restrict__ W1,
                                            const float* __restrict__ step_q,
                                            const float* __restrict__ b_fm,
                                            const float* __restrict__ W_fm,
                                            unsigned short* __restrict__ w1t,
                                            float* __restrict__ sqb,
                                            unsigned short* __restrict__ wfmt) {
    const int blk = blockIdx.x, tid = threadIdx.x;
    if (blk < 256) {
        const int o = blk * 256 + tid;          // o = n*256 + k
        const int n = o >> 8, k = o & 255;
        w1t[o] = f2bf(W1[(k << 8) + n]);
    } else if (blk == 256) {
        const float bv = b_fm[tid];
        #pragma unroll
        for (int t = 0; t < 24; ++t) sqb[t * 256 + tid] = step_q[t * 256 + tid] + bv;
    } else {
        const int n = tid;
        #pragma unroll
        for (int k = 0; k < 32; ++k)
            wfmt[(n << 5) + k] = (k < 16) ? f2bf(W_fm[(k << 8) + n]) : (unsigned short)0;
    }
}

__global__ __launch_bounds__(256, 6) void fused_head(
    const float* __restrict__ final_h, const float* __restrict__ future_met,
    const float* __restrict__ gamma,   const float* __restrict__ beta,
    const float* __restrict__ b1,      const float* __restrict__ W2,
    const float* __restrict__ b2,      const unsigned short* __restrict__ w1t,
    const float* __restrict__ sqb,     const unsigned short* __restrict__ wfmt,
    float* __restrict__ out)
{
    __shared__ __align__(16) unsigned short Abuf[MROWS * LDA];  // 16896 B
    __shared__ __align__(16) unsigned short fmA[MROWS * FMS];   //  2560 B
    __shared__ float2 red[4][MROWS];                            //  1024 B
    __shared__ float2 mv[MROWS];                                //   256 B
    __shared__ float  part[4][MROWS];                           //   512 B

    const int tid = threadIdx.x;
    const int w   = tid >> 6;
    const int l   = tid & 63;
    const int col = l & 15;     // n within 16-tile (C layout); m for A frags
    const int qr  = l >> 4;     // quad row group
    const int m0  = blockIdx.x * MROWS;

    // ---- stage fm rows as bf16 (k 0..15), zero-pad k 16..31 ----
    if (tid < 128) {
        const int row = tid >> 2, f0 = (tid & 3) << 2;
        const int m  = m0 + row;
        const int bn = m / 24, tt = m - bn * 24;
        const int b  = bn / 1000, n = bn - b * 1000;
        const float4 v = *(const float4*)&future_met[((((b * 24 + tt) * 1000) + n) << 4) + f0];
        ushort2 lo = pk_bf16(v.x, v.y), hi = pk_bf16(v.z, v.w);
        ushort4 o; o.x = lo.x; o.y = lo.y; o.z = hi.x; o.w = hi.y;
        *(ushort4*)&fmA[row * FMS + f0] = o;
    }
    {
        const int row = tid >> 3, k = 16 + ((tid & 7) << 1);
        *(unsigned int*)&fmA[row * FMS + k] = 0u;
    }
    __syncthreads();

    // ---- phase A: C init = final_h + (step_q + b_fm), in MFMA C layout ----
    f32x4 acc[2][4];
    #pragma unroll
    for (int i = 0; i < 2; ++i) {
        #pragma unroll
        for (int r = 0; r < 4; ++r) {
            const int m  = (i << 4) + (qr << 2) + r;
            const int mm = m0 + m;
            const int bn = mm / 24, tt = mm - bn * 24;
            const float* fh = final_h + (bn << 8) + (w << 6) + col;
            const float* sb = sqb + (tt << 8) + (w << 6) + col;
            #pragma unroll
            for (int j = 0; j < 4; ++j)
                acc[i][j][r] = fh[j << 4] + sb[j << 4];
        }
    }
    // fm @ W_fm via MFMA (K=32, upper half zeros)
    {
        const bf16x8 af0 = *(const bf16x8*)&fmA[col * FMS + (qr << 3)];
        const bf16x8 af1 = *(const bf16x8*)&fmA[(16 + col) * FMS + (qr << 3)];
        #pragma unroll
        for (int j = 0; j < 4; ++j) {
            const bf16x8 bf = *(const bf16x8*)&wfmt[(((w << 6) + (j << 4) + col) << 5) + (qr << 3)];
            acc[0][j] = __builtin_amdgcn_mfma_f32_16x16x32_bf16(af0, bf, acc[0][j], 0, 0, 0);
            acc[1][j] = __builtin_amdgcn_mfma_f32_16x16x32_bf16(af1, bf, acc[1][j], 0, 0, 0);
        }
    }

    // ---- LayerNorm stats on C-layout accumulator ----
    #pragma unroll
    for (int i = 0; i < 2; ++i) {
        #pragma unroll
        for (int r = 0; r < 4; ++r) {
            float s = 0.f, q = 0.f;
            #pragma unroll
            for (int j = 0; j < 4; ++j) { const float v = acc[i][j][r]; s += v; q = fmaf(v, v, q); }
            s += __shfl_xor(s, 1); q += __shfl_xor(q, 1);
            s += __shfl_xor(s, 2); q += __shfl_xor(q, 2);
            s += __shfl_xor(s, 4); q += __shfl_xor(q, 4);
            s += __shfl_xor(s, 8); q += __shfl_xor(q, 8);
            if (col == 0) red[w][(i << 4) + (qr << 2) + r] = make_float2(s, q);
        }
    }
    __syncthreads();
    if (tid < MROWS) {
        const float2 a0 = red[0][tid], a1 = red[1][tid], a2 = red[2][tid], a3 = red[3][tid];
        const float S = a0.x + a1.x + a2.x + a3.x;
        const float Q = a0.y + a1.y + a2.y + a3.y;
        const float mu = S * 0.00390625f;
        const float rstd = rsqrtf(Q * 0.00390625f - mu * mu + 1e-5f);
        mv[tid] = make_float2(mu, rstd);
    }
    __syncthreads();

    // ---- normalize (folded: v*(rstd*g) + (beta - mu*rstd*g)) -> bf16 Abuf ----
    #pragma unroll
    for (int i = 0; i < 2; ++i) {
        #pragma unroll
        for (int r = 0; r < 4; ++r) {
            const int m = (i << 4) + (qr << 2) + r;
            const float2 p = mv[m];
            float vj[4];
            #pragma unroll
            for (int j = 0; j < 4; ++j) {
                const int n = (w << 6) + (j << 4) + col;
                const float s1 = p.y * gamma[n];
                const float s2 = fmaf(-p.x, s1, beta[n]);
                vj[j] = fmaf(acc[i][j][r], s1, s2);
            }
            const ushort2 p01 = pk_bf16(vj[0], vj[1]);
            const ushort2 p23 = pk_bf16(vj[2], vj[3]);
            unsigned short* Ab = &Abuf[m * LDA + (w << 6) + col];
            Ab[0]  = p01.x; Ab[16] = p01.y;
            Ab[32] = p23.x; Ab[48] = p23.y;
        }
    }
    __syncthreads();

    // ---- phase 2: (32x256) @ W1 via MFMA ----
    #pragma unroll
    for (int i = 0; i < 2; ++i)
        #pragma unroll
        for (int j = 0; j < 4; ++j)
            acc[i][j] = (f32x4){0.f, 0.f, 0.f, 0.f};

    {
        const unsigned short* Bbase = w1t + (((w << 6) + col) << 8) + (qr << 3);
        const unsigned short* Ab0 = &Abuf[col * LDA + (qr << 3)];
        const unsigned short* Ab1 = &Abuf[(16 + col) * LDA + (qr << 3)];
        #pragma unroll
        for (int kk = 0; kk < 8; ++kk) {
            const bf16x8 a0 = *(const bf16x8*)(Ab0 + (kk << 5));
            const bf16x8 a1 = *(const bf16x8*)(Ab1 + (kk << 5));
            #pragma unroll
            for (int j = 0; j < 4; ++j) {
                const bf16x8 bf = *(const bf16x8*)(Bbase + (j << 12) + (kk << 5));
                acc[0][j] = __builtin_amdgcn_mfma_f32_16x16x32_bf16(a0, bf, acc[0][j], 0, 0, 0);
                acc[1][j] = __builtin_amdgcn_mfma_f32_16x16x32_bf16(a1, bf, acc[1][j], 0, 0, 0);
            }
        }
    }

    // ---- epilogue: +b1, fast gelu, dot W2, reduce ----
    {
        float b1v[4], w2v[4];
        #pragma unroll
        for (int j = 0; j < 4; ++j) {
            const int n = (w << 6) + (j << 4) + col;
            b1v[j] = b1[n]; w2v[j] = W2[n];
        }
        #pragma unroll
        for (int i = 0; i < 2; ++i) {
            #pragma unroll
            for (int r = 0; r < 4; ++r) {
                float p = 0.f;
                #pragma unroll
                for (int j = 0; j < 4; ++j) {
                    const float g = gelu_fast(acc[i][j][r] + b1v[j]);
                    p = fmaf(g, w2v[j], p);
                }
                p += __shfl_xor(p, 1);
                p += __shfl_xor(p, 2);
                p += __shfl_xor(p, 4);
                p += __shfl_xor(p, 8);
                if (col == 0) part[w][(i << 4) + (qr << 2) + r] = p;
            }
        }
    }
    __syncthreads();

    if (tid < MROWS) {
        const int m = m0 + tid;
        const float val = part[0][tid] + part[1][tid] + part[2][tid] + part[3][tid] + b2[0];
        const int bn = m / 24, tt = m - bn * 24;
        const int b  = bn / 1000, n = bn - b * 1000;
        out[(b * 24 + tt) * 1000 + n] = val;
    }
}

extern "C" void kernel_launch(void* const* d_in, const int* in_sizes, int n_in,
                              void* d_out, int out_size, void* d_ws, size_t ws_size,
                              hipStream_t stream) {
    const float* final_h    = (const float*)d_in[0];
    const float* future_met = (const float*)d_in[1];
    const float* step_q     = (const float*)d_in[2];
    const float* W_fm       = (const float*)d_in[3];
    const float* b_fm       = (const float*)d_in[4];
    const float* gamma      = (const float*)d_in[5];
    const float* beta       = (const float*)d_in[6];
    const float* W1         = (const float*)d_in[7];
    const float* b1         = (const float*)d_in[8];
    const float* W2         = (const float*)d_in[9];
    const float* b2         = (const float*)d_in[10];

    unsigned short* w1t  = (unsigned short*)d_ws;                  // 131072 B
    float*          sqb  = (float*)((char*)d_ws + 131072);         //  24576 B
    unsigned short* wfmt = (unsigned short*)((char*)d_ws + 155648);//  16384 B
    float* out = (float*)d_out;

    prep<<<258, 256, 0, stream>>>(W1, step_q, b_fm, W_fm, w1t, sqb, wfmt);
    fused_head<<<12000, 256, 0, stream>>>(final_h, future_met, gamma, beta, b1, W2, b2,
                                          w1t, sqb, wfmt, out);
}

// Round 5
// 229.481 us; speedup vs baseline: 1.3638x; 1.3638x over previous
//
#include <hip/hip_runtime.h>
#include <hip/hip_bf16.h>
#include <stdint.h>

#define MROWS 32
#define LDA   264   // Abuf stride in bf16 elems: 528 B/row (16B-aligned, bank-skewed)
#define FMS   40    // fmA stride in bf16 elems (80 B, 16B-aligned)

typedef __bf16 bf16x8 __attribute__((ext_vector_type(8)));
typedef float  f32x4  __attribute__((ext_vector_type(4)));

__device__ __forceinline__ unsigned short f2bf(float f) {
    union { float f; uint32_t u; } v; v.f = f;
    return (unsigned short)((v.u + 0x7FFFu + ((v.u >> 16) & 1u)) >> 16);
}

__device__ __forceinline__ ushort2 pk_bf16(float a, float b) {
    union { __hip_bfloat162 v; ushort2 u; } c;
    c.v = __float22bfloat162_rn(make_float2(a, b));
    return c.u;
}

// tanh-form GeLU via sigmoid; explicit rcp (avoids IEEE div sequence).
// max abs deviation from exact-erf gelu ~3e-4.
__device__ __forceinline__ float gelu_fast(float v) {
    const float t = v * v;
    const float p = fmaf(0.044715f, t, 1.0f);
    const float u = v * p;
    const float e = __builtin_amdgcn_exp2f(u * -2.3021131160186336f);  // exp(-2*0.79788456*u)
    return v * __builtin_amdgcn_rcpf(1.0f + e);
}

// prep:
//  blocks 0..255 -> w1frag: W1 in MFMA B-fragment order.
//     elem index = (w*32 + j*8 + kk)*512 + l*8 + e  maps to
//     n = w*64 + j*16 + (l&15), k = kk*32 + (l>>4)*8 + e; value = bf16(W1[k*256+n]).
//     => every phase-2 B-load is 64 lanes x contiguous 16B = 1KB coalesced.
//  block 256 -> sqb (fp32 step_q + b_fm, 24x256)
//  block 257 -> wfmfrag: W_fm in same fragment order (K padded 16->32 with zeros):
//     elem index = (w*4 + j)*512 + l*8 + e; n = w*64+j*16+(l&15), k = (l>>4)*8+e (0 if k>=16)
__global__ __launch_bounds__(256) void prep(const float* __restrict__ W1,
                                            const float* __restrict__ step_q,
                                            const float* __restrict__ b_fm,
                                            const float* __restrict__ W_fm,
                                            unsigned short* __restrict__ w1frag,
                                            float* __restrict__ sqb,
                                            unsigned short* __restrict__ wfmfrag) {
    const int blk = blockIdx.x, tid = threadIdx.x;
    if (blk < 256) {
        const int o  = blk * 256 + tid;        // 0..65535, one bf16 elem each
        const int e  = o & 7;
        const int l  = (o >> 3) & 63;
        const int fr = o >> 9;                 // 0..127 = w*32 + j*8 + kk
        const int kk = fr & 7, j = (fr >> 3) & 3, w = fr >> 5;
        const int col = l & 15, qr = l >> 4;
        const int n = (w << 6) + (j << 4) + col;
        const int k = (kk << 5) + (qr << 3) + e;
        w1frag[o] = f2bf(W1[(k << 8) + n]);
    } else if (blk == 256) {
        const float bv = b_fm[tid];
        #pragma unroll
        for (int t = 0; t < 24; ++t) sqb[t * 256 + tid] = step_q[t * 256 + tid] + bv;
    } else {
        // 1024 fragments (w,j,l) x 8 elems = 16384 elems; 4 fragments per thread
        #pragma unroll
        for (int f = 0; f < 4; ++f) {
            const int fr = (f << 8) + tid;     // 0..1023 = w*256 + j*64 + l
            const int l = fr & 63, j = (fr >> 6) & 3, w = fr >> 8;
            const int col = l & 15, qr = l >> 4;
            const int n = (w << 6) + (j << 4) + col;
            #pragma unroll
            for (int e = 0; e < 8; ++e) {
                const int k = (qr << 3) + e;
                wfmfrag[(fr << 3) + e] = (k < 16) ? f2bf(W_fm[(k << 8) + n]) : (unsigned short)0;
            }
        }
    }
}

__global__ __launch_bounds__(256, 6) void fused_head(
    const float* __restrict__ final_h, const float* __restrict__ future_met,
    const float* __restrict__ gamma,   const float* __restrict__ beta,
    const float* __restrict__ b1,      const float* __restrict__ W2,
    const float* __restrict__ b2,      const unsigned short* __restrict__ w1frag,
    const float* __restrict__ sqb,     const unsigned short* __restrict__ wfmfrag,
    float* __restrict__ out)
{
    __shared__ __align__(16) unsigned short Abuf[MROWS * LDA];  // 16896 B
    __shared__ __align__(16) unsigned short fmA[MROWS * FMS];   //  2560 B
    __shared__ float2 red[4][MROWS];                            //  1024 B
    __shared__ float2 mv[MROWS];                                //   256 B
    __shared__ float  part[4][MROWS];                           //   512 B

    const int tid = threadIdx.x;
    const int w   = tid >> 6;
    const int l   = tid & 63;
    const int col = l & 15;     // n within 16-tile (C layout); m for A frags
    const int qr  = l >> 4;     // quad row group
    const int m0  = blockIdx.x * MROWS;

    // ---- stage fm rows as bf16 (k 0..15), zero-pad k 16..31 ----
    if (tid < 128) {
        const int row = tid >> 2, f0 = (tid & 3) << 2;
        const int m  = m0 + row;
        const int bn = m / 24, tt = m - bn * 24;
        const int b  = bn / 1000, n = bn - b * 1000;
        const float4 v = *(const float4*)&future_met[((((b * 24 + tt) * 1000) + n) << 4) + f0];
        ushort2 lo = pk_bf16(v.x, v.y), hi = pk_bf16(v.z, v.w);
        ushort4 o; o.x = lo.x; o.y = lo.y; o.z = hi.x; o.w = hi.y;
        *(ushort4*)&fmA[row * FMS + f0] = o;
    }
    {
        const int row = tid >> 3, k = 16 + ((tid & 7) << 1);
        *(unsigned int*)&fmA[row * FMS + k] = 0u;
    }
    __syncthreads();

    // ---- phase A: C init = final_h + (step_q + b_fm), in MFMA C layout ----
    f32x4 acc[2][4];
    #pragma unroll
    for (int i = 0; i < 2; ++i) {
        #pragma unroll
        for (int r = 0; r < 4; ++r) {
            const int m  = (i << 4) + (qr << 2) + r;
            const int mm = m0 + m;
            const int bn = mm / 24, tt = mm - bn * 24;
            const float* fh = final_h + (bn << 8) + (w << 6) + col;
            const float* sb = sqb + (tt << 8) + (w << 6) + col;
            #pragma unroll
            for (int j = 0; j < 4; ++j)
                acc[i][j][r] = fh[j << 4] + sb[j << 4];
        }
    }
    // fm @ W_fm via MFMA (K=32, upper half zeros); fragment-ordered B loads
    {
        const bf16x8 af0 = *(const bf16x8*)&fmA[col * FMS + (qr << 3)];
        const bf16x8 af1 = *(const bf16x8*)&fmA[(16 + col) * FMS + (qr << 3)];
        const unsigned short* Bwf = wfmfrag + (w << 11) + (l << 3);
        #pragma unroll
        for (int j = 0; j < 4; ++j) {
            const bf16x8 bf = *(const bf16x8*)(Bwf + (j << 9));
            acc[0][j] = __builtin_amdgcn_mfma_f32_16x16x32_bf16(af0, bf, acc[0][j], 0, 0, 0);
            acc[1][j] = __builtin_amdgcn_mfma_f32_16x16x32_bf16(af1, bf, acc[1][j], 0, 0, 0);
        }
    }

    // ---- LayerNorm stats on C-layout accumulator ----
    #pragma unroll
    for (int i = 0; i < 2; ++i) {
        #pragma unroll
        for (int r = 0; r < 4; ++r) {
            float s = 0.f, q = 0.f;
            #pragma unroll
            for (int j = 0; j < 4; ++j) { const float v = acc[i][j][r]; s += v; q = fmaf(v, v, q); }
            s += __shfl_xor(s, 1); q += __shfl_xor(q, 1);
            s += __shfl_xor(s, 2); q += __shfl_xor(q, 2);
            s += __shfl_xor(s, 4); q += __shfl_xor(q, 4);
            s += __shfl_xor(s, 8); q += __shfl_xor(q, 8);
            if (col == 0) red[w][(i << 4) + (qr << 2) + r] = make_float2(s, q);
        }
    }
    __syncthreads();
    if (tid < MROWS) {
        const float2 a0 = red[0][tid], a1 = red[1][tid], a2 = red[2][tid], a3 = red[3][tid];
        const float S = a0.x + a1.x + a2.x + a3.x;
        const float Q = a0.y + a1.y + a2.y + a3.y;
        const float mu = S * 0.00390625f;
        const float rstd = rsqrtf(Q * 0.00390625f - mu * mu + 1e-5f);
        mv[tid] = make_float2(mu, rstd);
    }
    __syncthreads();

    // ---- normalize (folded: v*(rstd*g) + (beta - mu*rstd*g)) -> bf16 Abuf ----
    #pragma unroll
    for (int i = 0; i < 2; ++i) {
        #pragma unroll
        for (int r = 0; r < 4; ++r) {
            const int m = (i << 4) + (qr << 2) + r;
            const float2 p = mv[m];
            float vj[4];
            #pragma unroll
            for (int j = 0; j < 4; ++j) {
                const int n = (w << 6) + (j << 4) + col;
                const float s1 = p.y * gamma[n];
                const float s2 = fmaf(-p.x, s1, beta[n]);
                vj[j] = fmaf(acc[i][j][r], s1, s2);
            }
            const ushort2 p01 = pk_bf16(vj[0], vj[1]);
            const ushort2 p23 = pk_bf16(vj[2], vj[3]);
            unsigned short* Ab = &Abuf[m * LDA + (w << 6) + col];
            Ab[0]  = p01.x; Ab[16] = p01.y;
            Ab[32] = p23.x; Ab[48] = p23.y;
        }
    }
    __syncthreads();

    // ---- phase 2: (32x256) @ W1 via MFMA; fragment-ordered coalesced B loads ----
    #pragma unroll
    for (int i = 0; i < 2; ++i)
        #pragma unroll
        for (int j = 0; j < 4; ++j)
            acc[i][j] = (f32x4){0.f, 0.f, 0.f, 0.f};

    {
        const unsigned short* Bw  = w1frag + (w << 14) + (l << 3);
        const unsigned short* Ab0 = &Abuf[col * LDA + (qr << 3)];
        const unsigned short* Ab1 = &Abuf[(16 + col) * LDA + (qr << 3)];
        #pragma unroll
        for (int kk = 0; kk < 8; ++kk) {
            const bf16x8 a0 = *(const bf16x8*)(Ab0 + (kk << 5));
            const bf16x8 a1 = *(const bf16x8*)(Ab1 + (kk << 5));
            #pragma unroll
            for (int j = 0; j < 4; ++j) {
                const bf16x8 bf = *(const bf16x8*)(Bw + (j << 12) + (kk << 9));
                acc[0][j] = __builtin_amdgcn_mfma_f32_16x16x32_bf16(a0, bf, acc[0][j], 0, 0, 0);
                acc[1][j] = __builtin_amdgcn_mfma_f32_16x16x32_bf16(a1, bf, acc[1][j], 0, 0, 0);
            }
        }
    }

    // ---- epilogue: +b1, fast gelu, dot W2, reduce ----
    {
        float b1v[4], w2v[4];
        #pragma unroll
        for (int j = 0; j < 4; ++j) {
            const int n = (w << 6) + (j << 4) + col;
            b1v[j] = b1[n]; w2v[j] = W2[n];
        }
        #pragma unroll
        for (int i = 0; i < 2; ++i) {
            #pragma unroll
            for (int r = 0; r < 4; ++r) {
                float p = 0.f;
                #pragma unroll
                for (int j = 0; j < 4; ++j) {
                    const float g = gelu_fast(acc[i][j][r] + b1v[j]);
                    p = fmaf(g, w2v[j], p);
                }
                p += __shfl_xor(p, 1);
                p += __shfl_xor(p, 2);
                p += __shfl_xor(p, 4);
                p += __shfl_xor(p, 8);
                if (col == 0) part[w][(i << 4) + (qr << 2) + r] = p;
            }
        }
    }
    __syncthreads();

    if (tid < MROWS) {
        const int m = m0 + tid;
        const float val = part[0][tid] + part[1][tid] + part[2][tid] + part[3][tid] + b2[0];
        const int bn = m / 24, tt = m - bn * 24;
        const int b  = bn / 1000, n = bn - b * 1000;
        out[(b * 24 + tt) * 1000 + n] = val;
    }
}

extern "C" void kernel_launch(void* const* d_in, const int* in_sizes, int n_in,
                              void* d_out, int out_size, void* d_ws, size_t ws_size,
                              hipStream_t stream) {
    const float* final_h    = (const float*)d_in[0];
    const float* future_met = (const float*)d_in[1];
    const float* step_q     = (const float*)d_in[2];
    const float* W_fm       = (const float*)d_in[3];
    const float* b_fm       = (const float*)d_in[4];
    const float* gamma      = (const float*)d_in[5];
    const float* beta       = (const float*)d_in[6];
    const float* W1         = (const float*)d_in[7];
    const float* b1         = (const float*)d_in[8];
    const float* W2         = (const float*)d_in[9];
    const float* b2         = (const float*)d_in[10];

    unsigned short* w1frag  = (unsigned short*)d_ws;                    // 131072 B
    float*          sqb     = (float*)((char*)d_ws + 131072);           //  24576 B
    unsigned short* wfmfrag = (unsigned short*)((char*)d_ws + 155648);  //  32768 B
    float* out = (float*)d_out;

    prep<<<258, 256, 0, stream>>>(W1, step_q, b_fm, W_fm, w1frag, sqb, wfmfrag);
    fused_head<<<12000, 256, 0, stream>>>(final_h, future_met, gamma, beta, b1, W2, b2,
                                          w1frag, sqb, wfmfrag, out);
}